// Round 6
// baseline (272.623 us; speedup 1.0000x reference)
//
#include <hip/hip_runtime.h>
#include <hip/hip_bf16.h>

#define NN 4
#define LL 8192
#define HH 8
#define DD 64
#define NH 32                 // n*h combos
#define RS  (HH*DD)           // 512 floats per s row (all heads)
#define KV_ELEMS 4160         // 64x64 kv + ksum[64]
#define CCH 128               // C-kernel l-chunks per n

typedef __attribute__((ext_vector_type(8))) short bf16x8;   // 8 bf16 (4 VGPR)
typedef __attribute__((ext_vector_type(4))) float f32x4;

__device__ __forceinline__ float phi(float x) {
  // elu(x*temp) + 1 ; temp = 64^(-0.25)
  float t = x * 0.35355339059327373f;
  return t > 0.f ? t + 1.f : __expf(t);
}
__device__ __forceinline__ short f2bf(float x) {
  __hip_bfloat16 h = __float2bfloat16(x);                  // RN
  return (short)__builtin_bit_cast(unsigned short, h);
}
__device__ __forceinline__ float bf2f(short s) {
  __hip_bfloat16 h = __builtin_bit_cast(__hip_bfloat16, (unsigned short)s);
  return __bfloat162float(h);
}
__device__ __forceinline__ void split2(float x, short& hi, short& lo) {
  hi = f2bf(x);
  lo = f2bf(x - bf2f(hi));
}
#define MFMA16 __builtin_amdgcn_mfma_f32_16x16x32_bf16

// Barrier WITHOUT the compiler's vmcnt(0) drain: LDS visibility only.
// Prefetched global loads stay in flight across it (T3/T4); their waits are the
// compiler's counted vmcnt at first use. sched_barrier pins ordering (rule #18).
#define BARRIER_NOVM() do {                                   \
    asm volatile("s_waitcnt lgkmcnt(0)" ::: "memory");        \
    __builtin_amdgcn_sched_barrier(0);                        \
    __builtin_amdgcn_s_barrier();                             \
    __builtin_amdgcn_sched_barrier(0);                        \
  } while (0)

// ---------------- Kernel A: partial kv[d][m] += phi(K)^T V via MFMA, h-fused ----------------
// v7: v3-v6 all pinned at 59-70us with every pipe idle -> diagnosis: vmcnt(0)
// drain at every __syncthreads serialized [load 256KB] -> [2k cyc compute] per
// step; memory never continuously busy. Fix: raw lgkm-only barriers + 2-step
// register prefetch (two NAMED buffer sets, loop unrolled x2 - no runtime reg
// indexing). Everything else (swizzled [col][32s] bf16 planes, 48 split-mfma
// per step, h-fused contiguous reads) identical to v6 (passed 2.4e-4).
__global__ __launch_bounds__(512, 1) void kv_partial_kernel(
    const float* __restrict__ K, const float* __restrict__ V,
    float* __restrict__ part, int sch)
{
  const int n = blockIdx.x / sch, chunk = blockIdx.x % sch;
  const int tid = threadIdx.x;
  const int w = tid >> 6, lane = tid & 63;    // w = head
  const int q = lane >> 4, p = lane & 15;
  const int cq = tid >> 7;                    // loader: 8-row chunk 0..3
  const int cg = tid & 127;                   // loader: col-group (4 cols)
  const int rows_pb = LL / sch;               // 128 at sch=64
  const int nsteps = rows_pb / 32;            // 4 (always even for sch<=256)

  const float* kbase = K + ((size_t)n * LL + (size_t)chunk * rows_pb) * RS;
  const float* vbase = V + ((size_t)n * LL + (size_t)chunk * rows_pb) * RS;

  // planes: 0=K.hi 1=K.lo 2=V.hi 3=V.lo ; [col][32 s] chunk-swizzled; 128 KB
  __shared__ short pl[4][512 * 32];

  f32x4 acc[4][4] = {};                       // [dt][mt] 16x16 tiles
  float ksacc[4] = {0.f, 0.f, 0.f, 0.f};
  f32x4 krA[8], vrA[8], krB[8], vrB[8];       // 2-deep prefetch (named: rule #20)

  auto loadregs = [&](int T, f32x4 (&kr)[8], f32x4 (&vr)[8]) {
    const float* kp = kbase + (size_t)(T * 32 + cq * 8) * RS + 4 * cg;
    const float* vp = vbase + (size_t)(T * 32 + cq * 8) * RS + 4 * cg;
#pragma unroll
    for (int u = 0; u < 8; ++u) {
      kr[u] = *(const f32x4*)(kp + (size_t)u * RS);
      vr[u] = *(const f32x4*)(vp + (size_t)u * RS);
    }
  };
  auto cw = [&](f32x4 (&kr)[8], f32x4 (&vr)[8]) {   // convert + swizzled write
#pragma unroll
    for (int j = 0; j < 4; ++j) {
      const int col = 4 * cg + j;
      const int pos = (cq ^ ((col ^ (col >> 2)) & 3)) * 8;
      bf16x8 kh, kl, vh, vl;
      float s = 0.f;
#pragma unroll
      for (int u = 0; u < 8; ++u) {
        float f = phi(kr[u][j]);
        s += f;
        short a, b;
        split2(f, a, b);          kh[u] = a; kl[u] = b;
        split2(vr[u][j], a, b);   vh[u] = a; vl[u] = b;
      }
      ksacc[j] += s;
      *(bf16x8*)&pl[0][col * 32 + pos] = kh;
      *(bf16x8*)&pl[1][col * 32 + pos] = kl;
      *(bf16x8*)&pl[2][col * 32 + pos] = vh;
      *(bf16x8*)&pl[3][col * 32 + pos] = vl;
    }
  };
  auto mfma_step = [&]() {
    bf16x8 ah[4], al[4], bh[4], bl[4];
#pragma unroll
    for (int dt = 0; dt < 4; ++dt) {
      const int col = w * 64 + dt * 16 + p;
      const int pos = (q ^ ((col ^ (col >> 2)) & 3)) * 8;
      ah[dt] = *(const bf16x8*)&pl[0][col * 32 + pos];
      al[dt] = *(const bf16x8*)&pl[1][col * 32 + pos];
      bh[dt] = *(const bf16x8*)&pl[2][col * 32 + pos];
      bl[dt] = *(const bf16x8*)&pl[3][col * 32 + pos];
    }
#pragma unroll
    for (int dt = 0; dt < 4; ++dt)
#pragma unroll
      for (int mt = 0; mt < 4; ++mt) {
        acc[dt][mt] = MFMA16(ah[dt], bh[mt], acc[dt][mt], 0, 0, 0);
        acc[dt][mt] = MFMA16(ah[dt], bl[mt], acc[dt][mt], 0, 0, 0);
        acc[dt][mt] = MFMA16(al[dt], bh[mt], acc[dt][mt], 0, 0, 0);
      }
  };

  loadregs(0, krA, vrA);
  loadregs(1, krB, vrB);
  for (int t = 0; t < nsteps; t += 2) {
    cw(krA, vrA);
    BARRIER_NOVM();
    if (t + 2 < nsteps) loadregs(t + 2, krA, vrA);
    mfma_step();
    BARRIER_NOVM();

    cw(krB, vrB);
    BARRIER_NOVM();
    if (t + 3 < nsteps) loadregs(t + 3, krB, vrB);
    mfma_step();
    BARRIER_NOVM();
  }

  // ---- store partial kv: D layout col=lane&15, row=quad*4+reg ----
  float* po = part + ((size_t)blockIdx.x * 8 + w) * KV_ELEMS;
#pragma unroll
  for (int dt = 0; dt < 4; ++dt)
#pragma unroll
    for (int mt = 0; mt < 4; ++mt)
#pragma unroll
      for (int r = 0; r < 4; ++r)
        po[(dt * 16 + q * 4 + r) * 64 + mt * 16 + p] = acc[dt][mt][r];

  // ---- ksum: per-thread col partials -> LDS reduce over the 4 cq groups ----
  float* ksl = (float*)pl;                    // pl free after last barrier
  f32x4 kq = {ksacc[0], ksacc[1], ksacc[2], ksacc[3]};
  *(f32x4*)&ksl[cq * 520 + 4 * cg] = kq;
  __syncthreads();
  {
    float s = ksl[tid] + ksl[520 + tid] + ksl[1040 + tid] + ksl[1560 + tid];
    part[((size_t)blockIdx.x * 8 + (tid >> 6)) * KV_ELEMS + 4096 + (tid & 63)] = s;
  }
}

// ---------------- Kernel B: reduce partials; emit kv m-major split hi/lo + ksum ----------------
__global__ __launch_bounds__(256) void kv_reduce_kernel(
    const float* __restrict__ part, short* __restrict__ kvh,
    short* __restrict__ kvl, float* __restrict__ ksum, int np)
{
  const int nh = blockIdx.x / 17;
  const int e  = (blockIdx.x % 17) * 256 + threadIdx.x;
  if (e >= KV_ELEMS) return;
  const int n = nh >> 3, hh = nh & 7;
  const float* pp = part + ((size_t)(n * np) * 8 + hh) * KV_ELEMS + e;
  float s = 0.f;
  for (int i = 0; i < np; ++i) s += pp[(size_t)i * 8 * KV_ELEMS];
  if (e < 4096) {
    const int d = e >> 6, m = e & 63;
    short hi, lo; split2(s, hi, lo);
    kvh[(size_t)nh * 4096 + m * 64 + d] = hi;     // m-major: C's B-frags read
    kvl[(size_t)nh * 4096 + m * 64 + d] = lo;     // contiguous d-runs
  } else {
    ksum[(size_t)nh * 64 + (e - 4096)] = s;
  }
}

// ---------------- Kernel C: out[l][m] = z_l * (phi(Q) . kv) via MFMA, ALL 8 heads/block ------
// v7: __syncthreads -> lgkm-only raw barriers (same drain-removal as A); the
// already-issued next-tile loads now actually span the barrier.
__global__ __launch_bounds__(512, 2) void attn_out_kernel(
    const float* __restrict__ Q, const short* __restrict__ kvh,
    const short* __restrict__ kvl, const float* __restrict__ ksumg,
    float* __restrict__ out)
{
  const int n = blockIdx.x / CCH, chunk = blockIdx.x % CCH;
  const int tid = threadIdx.x;
  const int w = tid >> 6, lane = tid & 63;            // w = head
  const int q = lane >> 4, p = lane & 15;
  const int nh = n * 8 + w;
  const int rows_pb = LL / CCH;                       // 64
  const int nt = rows_pb / 16;                        // 4 tiles of 16 rows
  const int l_base = chunk * rows_pb;
  const int sr = tid >> 5, sc = (tid & 31) * 16;      // staging: row 0..15, col *16

  const float* qbase = Q + (size_t)n * LL * RS;

  __shared__ short qh[16][520];                       // phiQ hi plane, natural [l][h*64+d]
  __shared__ short ql[16][520];                       // phiQ lo plane

  // resident B frags for this wave's head: B[k=d][m], m-major kv
  bf16x8 bh[4][2], bl[4][2];
#pragma unroll
  for (int mt = 0; mt < 4; ++mt)
#pragma unroll
    for (int kst = 0; kst < 2; ++kst) {
      const size_t off = (size_t)nh * 4096 + (size_t)(mt * 16 + p) * 64 + kst * 32 + q * 8;
      bh[mt][kst] = *(const bf16x8*)(kvh + off);
      bl[mt][kst] = *(const bf16x8*)(kvl + off);
    }
  float ksr[2][8];
#pragma unroll
  for (int kst = 0; kst < 2; ++kst) {
    const float* kp = ksumg + (size_t)nh * 64 + kst * 32 + q * 8;
    f32x4 a = *(const f32x4*)(kp), b = *(const f32x4*)(kp + 4);
    ksr[kst][0]=a[0]; ksr[kst][1]=a[1]; ksr[kst][2]=a[2]; ksr[kst][3]=a[3];
    ksr[kst][4]=b[0]; ksr[kst][5]=b[1]; ksr[kst][6]=b[2]; ksr[kst][7]=b[3];
  }

  f32x4 qa[4], qb[4];
  auto loadq = [&](f32x4* R, int T) {
    const float* qp_ = qbase + (size_t)(l_base + T * 16 + sr) * RS + sc;
    R[0] = *(const f32x4*)(qp_);      R[1] = *(const f32x4*)(qp_ + 4);
    R[2] = *(const f32x4*)(qp_ + 8);  R[3] = *(const f32x4*)(qp_ + 12);
  };

  auto cbody = [&](const f32x4* R, int T) {
    // ---- stage: phi + hi/lo split, natural layout ----
    bf16x8 hv0, hv1, lv0, lv1;
#pragma unroll
    for (int r = 0; r < 2; ++r)
#pragma unroll
      for (int jj = 0; jj < 4; ++jj) {
        float f = phi(R[r][jj]);
        short hs, ls; split2(f, hs, ls);
        hv0[r * 4 + jj] = hs; lv0[r * 4 + jj] = ls;
      }
#pragma unroll
    for (int r = 0; r < 2; ++r)
#pragma unroll
      for (int jj = 0; jj < 4; ++jj) {
        float f = phi(R[r + 2][jj]);
        short hs, ls; split2(f, hs, ls);
        hv1[r * 4 + jj] = hs; lv1[r * 4 + jj] = ls;
      }
    *(bf16x8*)&qh[sr][sc]     = hv0;  *(bf16x8*)&qh[sr][sc + 8] = hv1;
    *(bf16x8*)&ql[sr][sc]     = lv0;  *(bf16x8*)&ql[sr][sc + 8] = lv1;
    BARRIER_NOVM();

    // ---- frag reads + z partial (LDS phase) ----
    f32x4 acc[4] = {};
    float zp = 0.f;
    bf16x8 ah[2], al[2];
#pragma unroll
    for (int kst = 0; kst < 2; ++kst) {
      const int cc = w * 64 + kst * 32 + q * 8;
      ah[kst] = *(const bf16x8*)&qh[p][cc];
      al[kst] = *(const bf16x8*)&ql[p][cc];
#pragma unroll
      for (int j = 0; j < 8; ++j)
        zp += (bf2f(ah[kst][j]) + bf2f(al[kst][j])) * ksr[kst][j];
    }
    BARRIER_NOVM();   // lgkm drained: frag reads complete; next stage may overwrite

    // ---- MFMA + z + scaled store (overlaps next tile's staging) ----
#pragma unroll
    for (int kst = 0; kst < 2; ++kst)
#pragma unroll
      for (int mt = 0; mt < 4; ++mt) {
        acc[mt] = MFMA16(ah[kst], bh[mt][kst], acc[mt], 0, 0, 0);
        acc[mt] = MFMA16(ah[kst], bl[mt][kst], acc[mt], 0, 0, 0);
        acc[mt] = MFMA16(al[kst], bh[mt][kst], acc[mt], 0, 0, 0);
      }
    zp += __shfl_xor(zp, 16, 64);
    zp += __shfl_xor(zp, 32, 64);
    const float z = 1.0f / (zp + 1e-6f);
    float zr[4];
#pragma unroll
    for (int r = 0; r < 4; ++r) zr[r] = __shfl(z, q * 4 + r, 64);

    const int l0 = l_base + T * 16;
#pragma unroll
    for (int mt = 0; mt < 4; ++mt)
#pragma unroll
      for (int r = 0; r < 4; ++r)
        out[((size_t)nh * LL + l0 + q * 4 + r) * DD + mt * 16 + p] = acc[mt][r] * zr[r];
  };

  loadq(qa, 0);
  for (int t = 0; t < nt; t += 2) {        // nt = 4 (even)
    loadq(qb, t + 1);
    cbody(qa, t);
    if (t + 2 < nt) loadq(qa, t + 2);
    cbody(qb, t + 1);
  }
}

extern "C" void kernel_launch(void* const* d_in, const int* in_sizes, int n_in,
                              void* d_out, int out_size, void* d_ws, size_t ws_size,
                              hipStream_t stream)
{
  const float* Q = (const float*)d_in[0];
  const float* K = (const float*)d_in[1];
  const float* V = (const float*)d_in[2];
  float* out = (float*)d_out;

  int sch = 64;                                        // s-chunks per n -> 256 blocks
  while (sch > 4) {
    size_t need = (size_t)NN * sch * 8 * KV_ELEMS * 4  // partials
                + (size_t)NH * 4096 * 2 * 2            // kvh + kvl (bf16)
                + (size_t)NH * 64 * 4;                 // ksum
    if (need <= ws_size) break;
    sch >>= 1;
  }
  float* part = (float*)d_ws;
  short* kvh  = (short*)((char*)d_ws + (size_t)NN * sch * 8 * KV_ELEMS * 4);
  short* kvl  = kvh + (size_t)NH * 4096;
  float* ksum = (float*)(kvl + (size_t)NH * 4096);

  hipLaunchKernelGGL(kv_partial_kernel, dim3(NN * sch), dim3(512), 0, stream,
                     K, V, part, sch);
  hipLaunchKernelGGL(kv_reduce_kernel, dim3(NH * 17), dim3(256), 0, stream,
                     part, kvh, kvl, ksum, sch);
  hipLaunchKernelGGL(attn_out_kernel, dim3(NN * CCH), dim3(512), 0, stream,
                     Q, kvh, kvl, ksum, out);
}